// Round 6
// baseline (100.800 us; speedup 1.0000x reference)
//
#include <hip/hip_runtime.h>
#include <hip/hip_bf16.h>
#include <math.h>

// SE (RBF) kernel attention via bf16 MFMA flash attention, prepacked K/V.
// score = (k2 - sqrt(max(q2 - 2 q.k + k2, 0)))/16  (q2 term cancels in softmax)
// Log2-units softmax: s~ = C*(k2 - dist), C = log2(e)/16; p = exp2(s~ - m~).
// R6: 4 waves x 32 queries/wave -> each K/V LDS fragment read feeds 2 MFMAs.
// Shared running max across the lane's 2 queries; per-query l.

typedef __attribute__((ext_vector_type(8))) short bf16x8;
typedef __attribute__((ext_vector_type(4))) float f32x4;

#define SEQ    2048
#define DIM    64
#define NHEAD  32
#define QBLK   128         // queries per block (4 waves x 32)
#define KVB    64          // keys per tile
#define NKT    (SEQ / KVB)
#define TILE_B 8192        // bytes per bf16 64x64 tile image
#define C2     0.0901684403f    // log2(e)/16
#define THR2   11.5415603f      // 8 * log2(e)

__device__ __forceinline__ float fast_exp2(float x) { return __builtin_amdgcn_exp2f(x); }
__device__ __forceinline__ float fast_sqrt(float x) { return __builtin_amdgcn_sqrtf(x); }

__device__ __forceinline__ unsigned int f2bf(float f) {
    __hip_bfloat16 h = __float2bfloat16(f);   // RNE
    unsigned short u;
    __builtin_memcpy(&u, &h, 2);
    return (unsigned int)u;
}

__device__ __forceinline__ void gl_lds16(const void* g, void* l) {
    __builtin_amdgcn_global_load_lds(
        (const __attribute__((address_space(1))) unsigned int*)g,
        (__attribute__((address_space(3))) unsigned int*)l, 16, 0, 0);
}

// ---------------- prepack: K/V -> bf16 swizzled tile images + k2, k2c --------
__global__ __launch_bounds__(256, 4)
void prep_kv(const float* __restrict__ Kg, const float* __restrict__ Vg,
             char* __restrict__ Kp, char* __restrict__ Vp,
             float* __restrict__ k2g, float* __restrict__ k2cg) {
    __shared__ char Kimg[TILE_B];
    __shared__ char Vimg[TILE_B];

    const int tid  = threadIdx.x;
    const int kt   = blockIdx.x;     // tile 0..31
    const int head = blockIdx.y;     // 0..31
    const size_t hb = (size_t)head * (SEQ * DIM);

    // ---- K tile: bf16 + swizzle + k2/k2c ----
    {
        const int row = tid >> 2;    // 0..63
        const int sc4 = tid & 3;     // 16-d chunk
        const float* kp = Kg + hb + (size_t)(kt * KVB + row) * DIM + sc4 * 16;
        f32x4 a = *(const f32x4*)kp;
        f32x4 b = *(const f32x4*)(kp + 4);
        f32x4 c = *(const f32x4*)(kp + 8);
        f32x4 d = *(const f32x4*)(kp + 12);
        float part = 0.f;
#pragma unroll
        for (int j = 0; j < 4; ++j)
            part += a[j]*a[j] + b[j]*b[j] + c[j]*c[j] + d[j]*d[j];
        part += __shfl_xor(part, 1);
        part += __shfl_xor(part, 2);
        if (sc4 == 0) {
            k2g[head * SEQ + kt * KVB + row]  = part;
            k2cg[head * SEQ + kt * KVB + row] = part * C2;
        }
        bf16x8 p0, p1;
#pragma unroll
        for (int j = 0; j < 4; ++j) {
            p0[j]     = (short)f2bf(a[j]);
            p0[4 + j] = (short)f2bf(b[j]);
            p1[j]     = (short)f2bf(c[j]);
            p1[4 + j] = (short)f2bf(d[j]);
        }
        const int sw = (row & 7) << 4;
        const int wa = row * 128 + sc4 * 32;
        *(bf16x8*)(Kimg + (wa ^ sw))        = p0;
        *(bf16x8*)(Kimg + ((wa + 16) ^ sw)) = p1;
    }
    // ---- V^T tile: bf16 pairs along k + swizzle ----
    {
        const int vpr = tid & 31;          // key pair (2*vpr, 2*vpr+1)
        const int vd0 = (tid >> 5) * 8;    // 8 d's
        const float* vp = Vg + hb + (size_t)(kt * KVB + 2 * vpr) * DIM + vd0;
        f32x4 a0 = *(const f32x4*)vp;
        f32x4 a1 = *(const f32x4*)(vp + 4);
        f32x4 b0 = *(const f32x4*)(vp + DIM);
        f32x4 b1 = *(const f32x4*)(vp + DIM + 4);
#pragma unroll
        for (int j = 0; j < 8; ++j) {
            const float lo = (j < 4) ? a0[j] : a1[j - 4];
            const float hi = (j < 4) ? b0[j] : b1[j - 4];
            const unsigned int pk = f2bf(lo) | (f2bf(hi) << 16);
            const int d  = vd0 + j;
            const int wa = d * 128 + vpr * 4;
            *(unsigned int*)(Vimg + (wa ^ ((d & 7) << 4))) = pk;
        }
    }
    __syncthreads();
    // ---- copy images to global, linear/coalesced ----
    char* kdst = Kp + (size_t)(head * NKT + kt) * TILE_B;
    char* vdst = Vp + (size_t)(head * NKT + kt) * TILE_B;
#pragma unroll
    for (int s = 0; s < 2; ++s) {
        *(f32x4*)(kdst + s * 4096 + tid * 16) = *(const f32x4*)(Kimg + s * 4096 + tid * 16);
        *(f32x4*)(vdst + s * 4096 + tid * 16) = *(const f32x4*)(Vimg + s * 4096 + tid * 16);
    }
}

// ---------------- main: flash attention over prepacked tiles -----------------
// 4 waves x 32 queries each; each K/V fragment read feeds 2 MFMAs.
__global__ __launch_bounds__(256, 2)
void se_attn_main(const float* __restrict__ Qg, const char* __restrict__ Kp,
                  const char* __restrict__ Vp, const float* __restrict__ k2g,
                  const float* __restrict__ k2cg, float* __restrict__ Og) {
    __shared__ char Kbuf[2][TILE_B];
    __shared__ char Vbuf[2][TILE_B];
    __shared__ char Pl[4][4096];         // per-wave P[32 q][64 k] bf16, swizzled

    const int tid = threadIdx.x;
    const int w   = tid >> 6;            // wave 0..3
    const int l   = tid & 63;
    const int lq  = l & 15;
    const int g   = l >> 4;
    const int head = blockIdx.y;
    const size_t hb = (size_t)head * (SEQ * DIM);
    const int qbase = blockIdx.x * QBLK + w * 32;
    char* Pw = Pl[w];
    const int swq = (lq & 7) << 4;       // row&7 == lq&7 for both qfrags

    const char*  Kph  = Kp + (size_t)head * NKT * TILE_B;
    const char*  Vph  = Vp + (size_t)head * NKT * TILE_B;
    const float* k2h  = k2g  + head * SEQ;
    const float* k2ch = k2cg + head * SEQ;

    // ---- Q B-fragments (2 qfrags x 2 K-halves) + q2 per qfrag ----
    bf16x8 qf[2][2];                     // [half][qfrag]
    float q2v[2];
#pragma unroll
    for (int j = 0; j < 2; ++j) {
        float q2 = 0.f;
#pragma unroll
        for (int h = 0; h < 2; ++h) {
            const float* qp = Qg + hb + (size_t)(qbase + j * 16 + lq) * DIM + h * 32 + g * 8;
            f32x4 a = *(const f32x4*)qp;
            f32x4 b = *(const f32x4*)(qp + 4);
#pragma unroll
            for (int e = 0; e < 4; ++e) {
                q2 += a[e] * a[e] + b[e] * b[e];
                qf[h][j][e]     = (short)f2bf(a[e]);
                qf[h][j][4 + e] = (short)f2bf(b[e]);
            }
        }
        q2 += __shfl_xor(q2, 16);
        q2 += __shfl_xor(q2, 32);
        q2v[j] = q2;
    }

    f32x4 ofr[4][2];                     // [d-block][qfrag]
#pragma unroll
    for (int i = 0; i < 4; ++i)
#pragma unroll
        for (int j = 0; j < 2; ++j) ofr[i][j] = (f32x4){0.f, 0.f, 0.f, 0.f};
    float m = -INFINITY, ls0 = 0.f, ls1 = 0.f;

    // prologue: stage tile 0 -> buf 0 (two 16B chunks per thread per buffer)
#pragma unroll
    for (int s = 0; s < 2; ++s) {
        gl_lds16(Kph + s * 4096 + tid * 16, Kbuf[0] + s * 4096 + w * 1024);
        gl_lds16(Vph + s * 4096 + tid * 16, Vbuf[0] + s * 4096 + w * 1024);
    }
    __syncthreads();

    int cur = 0;
    for (int kt = 0; kt < NKT; ++kt) {
        // k2 / k2c for this tile (issued before prefetch; shared across qfrags)
        f32x4 k2v[4], kcv[4];
#pragma unroll
        for (int f = 0; f < 4; ++f) {
            k2v[f] = *(const f32x4*)(k2h  + kt * KVB + f * 16 + g * 4);
            kcv[f] = *(const f32x4*)(k2ch + kt * KVB + f * 16 + g * 4);
        }

        // prefetch next tile into the other buffer
        if (kt + 1 < NKT) {
            const char* ktp = Kph + (size_t)(kt + 1) * TILE_B;
            const char* vtp = Vph + (size_t)(kt + 1) * TILE_B;
#pragma unroll
            for (int s = 0; s < 2; ++s) {
                gl_lds16(ktp + s * 4096 + tid * 16, Kbuf[cur ^ 1] + s * 4096 + w * 1024);
                gl_lds16(vtp + s * 4096 + tid * 16, Vbuf[cur ^ 1] + s * 4096 + w * 1024);
            }
        }

        const char* Kl = Kbuf[cur];
        const char* Vt = Vbuf[cur];

        // ---- QK^T (swapped): ST[k][q], each kf feeds both qfrags ----
        f32x4 st[4][2];
#pragma unroll
        for (int f = 0; f < 4; ++f)
#pragma unroll
            for (int j = 0; j < 2; ++j) st[f][j] = (f32x4){0.f, 0.f, 0.f, 0.f};
        __builtin_amdgcn_s_setprio(1);
#pragma unroll
        for (int f = 0; f < 4; ++f) {
#pragma unroll
            for (int h = 0; h < 2; ++h) {
                const int ra = (f * 16 + lq) * 128 + h * 64 + g * 16;
                bf16x8 kf = *(const bf16x8*)(Kl + (ra ^ swq));
                st[f][0] = __builtin_amdgcn_mfma_f32_16x16x32_bf16(kf, qf[h][0], st[f][0], 0, 0, 0);
                st[f][1] = __builtin_amdgcn_mfma_f32_16x16x32_bf16(kf, qf[h][1], st[f][1], 0, 0, 0);
            }
        }
        __builtin_amdgcn_s_setprio(0);

        // ---- scores (log2 units) + online softmax (shared m, per-q l) ----
        float sc[2][4][4];
        float tmf[4];
#pragma unroll
        for (int f = 0; f < 4; ++f) {
            float t0, t1;
#pragma unroll
            for (int j = 0; j < 2; ++j) {
#pragma unroll
                for (int r = 0; r < 4; ++r) {
                    const float sq = fmaxf(fmaf(-2.f, st[f][j][r], q2v[j] + k2v[f][r]), 0.f);
                    sc[j][f][r] = fmaf(-C2, fast_sqrt(sq), kcv[f][r]);
                }
            }
            t0 = fmaxf(fmaxf(sc[0][f][0], sc[0][f][1]), fmaxf(sc[0][f][2], sc[0][f][3]));
            t1 = fmaxf(fmaxf(sc[1][f][0], sc[1][f][1]), fmaxf(sc[1][f][2], sc[1][f][3]));
            tmf[f] = fmaxf(t0, t1);
        }
        float tmax = fmaxf(fmaxf(tmf[0], tmf[1]), fmaxf(tmf[2], tmf[3]));
        tmax = fmaxf(tmax, __shfl_xor(tmax, 16));
        tmax = fmaxf(tmax, __shfl_xor(tmax, 32));
        // defer-max (T13): only rescale when max grows by > 8 nats
        if (tmax > m + THR2) {
            const float scale = fast_exp2(m - tmax);   // 0 on first tile
            m = tmax;
            ls0 *= scale; ls1 *= scale;
#pragma unroll
            for (int i = 0; i < 4; ++i)
#pragma unroll
                for (int j = 0; j < 2; ++j) {
                    ofr[i][j][0] *= scale; ofr[i][j][1] *= scale;
                    ofr[i][j][2] *= scale; ofr[i][j][3] *= scale;
                }
        }
        // p = exp2(s~-m~), pack pairs, write per-wave P_lds[q][k]
#pragma unroll
        for (int j = 0; j < 2; ++j) {
#pragma unroll
            for (int f = 0; f < 4; ++f) {
#pragma unroll
                for (int e = 0; e < 2; ++e) {
                    const float p0 = fast_exp2(sc[j][f][2 * e]     - m);
                    const float p1 = fast_exp2(sc[j][f][2 * e + 1] - m);
                    if (j == 0) ls0 += p0 + p1; else ls1 += p0 + p1;
                    const unsigned int pk = f2bf(p0) | (f2bf(p1) << 16);
                    const int pr = 8 * f + 2 * g + e;
                    const int wa = (j * 16 + lq) * 128 + pr * 4;
                    *(unsigned int*)(Pw + (wa ^ swq)) = pk;
                }
            }
        }

        // ---- PV (swapped): O^T[d][q] += V^T . P^T, each vf feeds both qfrags
        bf16x8 pf[2][2];                 // [qfrag][half]
#pragma unroll
        for (int j = 0; j < 2; ++j)
#pragma unroll
            for (int h = 0; h < 2; ++h) {
                const int ra = (j * 16 + lq) * 128 + h * 64 + g * 16;
                pf[j][h] = *(const bf16x8*)(Pw + (ra ^ swq));
            }
        __builtin_amdgcn_s_setprio(1);
#pragma unroll
        for (int db = 0; db < 4; ++db) {
#pragma unroll
            for (int h = 0; h < 2; ++h) {
                const int ra = (db * 16 + lq) * 128 + h * 64 + g * 16;
                bf16x8 vf = *(const bf16x8*)(Vt + (ra ^ swq));
                ofr[db][0] = __builtin_amdgcn_mfma_f32_16x16x32_bf16(vf, pf[0][h], ofr[db][0], 0, 0, 0);
                ofr[db][1] = __builtin_amdgcn_mfma_f32_16x16x32_bf16(vf, pf[1][h], ofr[db][1], 0, 0, 0);
            }
        }
        __builtin_amdgcn_s_setprio(0);

        __syncthreads();   // drains stage loads + all reads of buf[cur]
        cur ^= 1;
    }

    // ---- finalize: per-qfrag l reduce, normalize, store ----
#pragma unroll
    for (int j = 0; j < 2; ++j) {
        float lsum = (j == 0) ? ls0 : ls1;
        lsum += __shfl_xor(lsum, 16);
        lsum += __shfl_xor(lsum, 32);
        const float inv = 1.f / lsum;
        float* op = Og + hb + (size_t)(qbase + j * 16 + lq) * DIM;
#pragma unroll
        for (int db = 0; db < 4; ++db) {
            f32x4 v;
#pragma unroll
            for (int r = 0; r < 4; ++r) v[r] = ofr[db][j][r] * inv;
            *(f32x4*)(op + db * 16 + g * 4) = v;   // d = 16*db + 4*g + r
        }
    }
}

// ---------------- fallback (no-workspace monolithic) -------------------------
__global__ __launch_bounds__(256, 4)
void se_attn_mfma(const float* __restrict__ Qg, const float* __restrict__ Kg,
                  const float* __restrict__ Vg, float* __restrict__ Og) {
    __shared__ char  Kl[KVB * 128];
    __shared__ char  Vt[DIM * 128];
    __shared__ char  Pl[4][16 * 128];
    __shared__ float k2s[KVB];

    const int tid = threadIdx.x;
    const int w   = tid >> 6;
    const int l   = tid & 63;
    const int lq  = l & 15;
    const int g   = l >> 4;
    const size_t hb = (size_t)blockIdx.y * (SEQ * DIM);
    const int q = blockIdx.x * 64 + w * 16 + lq;
    char* Pw = Pl[w];
    const int swq = (lq & 7) << 4;

    bf16x8 qf[2];
    float q2 = 0.f;
#pragma unroll
    for (int h = 0; h < 2; ++h) {
        const float* qp = Qg + hb + (size_t)q * DIM + h * 32 + g * 8;
        f32x4 a = *(const f32x4*)qp;
        f32x4 b = *(const f32x4*)(qp + 4);
#pragma unroll
        for (int j = 0; j < 4; ++j) {
            q2 += a[j] * a[j] + b[j] * b[j];
            qf[h][j]     = (short)f2bf(a[j]);
            qf[h][4 + j] = (short)f2bf(b[j]);
        }
    }
    q2 += __shfl_xor(q2, 16);
    q2 += __shfl_xor(q2, 32);

    f32x4 ofr[4];
#pragma unroll
    for (int i = 0; i < 4; ++i) ofr[i] = (f32x4){0.f, 0.f, 0.f, 0.f};
    float m = -INFINITY, lsum = 0.f;

    const int srow = tid >> 2;
    const int sc4  = tid & 3;
    const int vpr  = tid & 31;
    const int vd0  = (tid >> 5) * 8;

    for (int kt = 0; kt < NKT; ++kt) {
        __syncthreads();
        {
            const float* kp = Kg + hb + (size_t)(kt * KVB + srow) * DIM + sc4 * 16;
            f32x4 a = *(const f32x4*)kp;
            f32x4 b = *(const f32x4*)(kp + 4);
            f32x4 c = *(const f32x4*)(kp + 8);
            f32x4 d = *(const f32x4*)(kp + 12);
            float part = 0.f;
#pragma unroll
            for (int j = 0; j < 4; ++j)
                part += a[j]*a[j] + b[j]*b[j] + c[j]*c[j] + d[j]*d[j];
            part += __shfl_xor(part, 1);
            part += __shfl_xor(part, 2);
            if (sc4 == 0) k2s[srow] = part;
            bf16x8 p0, p1;
#pragma unroll
            for (int j = 0; j < 4; ++j) {
                p0[j]     = (short)f2bf(a[j]);
                p0[4 + j] = (short)f2bf(b[j]);
                p1[j]     = (short)f2bf(c[j]);
                p1[4 + j] = (short)f2bf(d[j]);
            }
            const int sw = (srow & 7) << 4;
            const int wa = srow * 128 + sc4 * 32;
            *(bf16x8*)(Kl + (wa ^ sw))        = p0;
            *(bf16x8*)(Kl + ((wa + 16) ^ sw)) = p1;
        }
        {
            const float* vp = Vg + hb + (size_t)(kt * KVB + 2 * vpr) * DIM + vd0;
            f32x4 a0 = *(const f32x4*)vp;
            f32x4 a1 = *(const f32x4*)(vp + 4);
            f32x4 b0 = *(const f32x4*)(vp + DIM);
            f32x4 b1 = *(const f32x4*)(vp + DIM + 4);
#pragma unroll
            for (int j = 0; j < 8; ++j) {
                const float lo = (j < 4) ? a0[j] : a1[j - 4];
                const float hi = (j < 4) ? b0[j] : b1[j - 4];
                const unsigned int pk = f2bf(lo) | (f2bf(hi) << 16);
                const int d = vd0 + j;
                const int wa = d * 128 + vpr * 4;
                *(unsigned int*)(Vt + (wa ^ ((d & 7) << 4))) = pk;
            }
        }
        __syncthreads();

        f32x4 st[4];
#pragma unroll
        for (int f = 0; f < 4; ++f) st[f] = (f32x4){0.f, 0.f, 0.f, 0.f};
#pragma unroll
        for (int f = 0; f < 4; ++f) {
#pragma unroll
            for (int h = 0; h < 2; ++h) {
                const int ra = (f * 16 + lq) * 128 + h * 64 + g * 16;
                bf16x8 kf = *(const bf16x8*)(Kl + (ra ^ swq));
                st[f] = __builtin_amdgcn_mfma_f32_16x16x32_bf16(kf, qf[h], st[f], 0, 0, 0);
            }
        }

        float sc[4][4];
        float tmax = -INFINITY;
#pragma unroll
        for (int f = 0; f < 4; ++f) {
            const f32x4 k2v = *(const f32x4*)(k2s + f * 16 + g * 4);
#pragma unroll
            for (int r = 0; r < 4; ++r) {
                const float kk = k2v[r];
                const float sq = fmaxf(fmaf(-2.f, st[f][r], q2 + kk), 0.f);
                const float s  = (kk - sqrtf(sq)) * 0.0625f;
                sc[f][r] = s;
                tmax = fmaxf(tmax, s);
            }
        }
        tmax = fmaxf(tmax, __shfl_xor(tmax, 16));
        tmax = fmaxf(tmax, __shfl_xor(tmax, 32));
        const float nm    = fmaxf(m, tmax);
        const float scale = __expf(m - nm);
        m = nm;
        lsum *= scale;
#pragma unroll
        for (int i = 0; i < 4; ++i) {
            ofr[i][0] *= scale; ofr[i][1] *= scale;
            ofr[i][2] *= scale; ofr[i][3] *= scale;
        }
#pragma unroll
        for (int f = 0; f < 4; ++f) {
#pragma unroll
            for (int e = 0; e < 2; ++e) {
                const float p0 = __expf(sc[f][2 * e]     - m);
                const float p1 = __expf(sc[f][2 * e + 1] - m);
                lsum += p0 + p1;
                const unsigned int pk = f2bf(p0) | (f2bf(p1) << 16);
                const int pr = 8 * f + 2 * g + e;
                const int wa = lq * 128 + pr * 4;
                *(unsigned int*)(Pw + (wa ^ swq)) = pk;
            }
        }

        bf16x8 pf[2];
#pragma unroll
        for (int h = 0; h < 2; ++h) {
            const int ra = lq * 128 + h * 64 + g * 16;
            pf[h] = *(const bf16x8*)(Pw + (ra ^ swq));
        }
#pragma unroll
        for (int db = 0; db < 4; ++db) {
#pragma unroll
            for (int h = 0; h < 2; ++h) {
                const int ra = (db * 16 + lq) * 128 + h * 64 + g * 16;
                bf16x8 vf = *(const bf16x8*)(Vt + (ra ^ swq));
                ofr[db] = __builtin_amdgcn_mfma_f32_16x16x32_bf16(vf, pf[h], ofr[db], 0, 0, 0);
            }
        }
    }

    lsum += __shfl_xor(lsum, 16);
    lsum += __shfl_xor(lsum, 32);
    const float inv = 1.f / lsum;
    float* op = Og + hb + (size_t)q * DIM;
#pragma unroll
    for (int db = 0; db < 4; ++db) {
#pragma unroll
        for (int r = 0; r < 4; ++r) {
            op[db * 16 + g * 4 + r] = ofr[db][r] * inv;
        }
    }
}

extern "C" void kernel_launch(void* const* d_in, const int* in_sizes, int n_in,
                              void* d_out, int out_size, void* d_ws, size_t ws_size,
                              hipStream_t stream) {
    const float* Q = (const float*)d_in[0];
    const float* K = (const float*)d_in[1];
    const float* V = (const float*)d_in[2];
    float* O = (float*)d_out;

    const size_t KP_B = (size_t)NHEAD * NKT * TILE_B;    // 8 MB
    const size_t K2_B = (size_t)NHEAD * SEQ * 4;         // 256 KB
    const size_t need = 2 * KP_B + 2 * K2_B;

    if (ws_size >= need) {
        char*  Kp  = (char*)d_ws;
        char*  Vp  = Kp + KP_B;
        float* k2  = (float*)(Kp + 2 * KP_B);
        float* k2c = (float*)((char*)k2 + K2_B);
        prep_kv<<<dim3(NKT, NHEAD), 256, 0, stream>>>(K, V, Kp, Vp, k2, k2c);
        se_attn_main<<<dim3(SEQ / QBLK, NHEAD), 256, 0, stream>>>(Q, Kp, Vp, k2, k2c, O);
    } else {
        se_attn_mfma<<<dim3(SEQ / 64, NHEAD), 256, 0, stream>>>(Q, K, V, O);
    }
}